// Round 18
// baseline (589.317 us; speedup 1.0000x reference)
//
#include <hip/hip_runtime.h>
#include <hip/hip_bf16.h>

typedef __hip_bfloat16 bf16;
typedef __attribute__((ext_vector_type(8))) short short8;
typedef __attribute__((ext_vector_type(4))) float f32x4;

#define HDIM 512
#define SLOPE 0.01f
#define BN_EPS 1e-5f
#define STRIPES 8

__device__ inline float bf2f(short s) {
    unsigned u = ((unsigned)(unsigned short)s) << 16;
    return __builtin_bit_cast(float, u);
}
__device__ inline unsigned short f2bfbits(float v) {
    bf16 h = __float2bfloat16(v);
    return (unsigned short)__builtin_bit_cast(short, h);
}

// ---------------- dtype detection + gpart zero-init ----------------
__global__ void detect_types(const int* __restrict__ ei, const unsigned* __restrict__ xw,
                             int* __restrict__ flags, float* __restrict__ gpart) {
    __shared__ int nzhi, okbf;
    if (threadIdx.x == 0) { nzhi = 0; okbf = 0; }
    __syncthreads();
    int lo = 0, ok = 0;
    for (int i = threadIdx.x; i < 2048; i += 256)
        if (ei[2 * i + 1] != 0) lo++;
    for (int i = threadIdx.x; i < 1024; i += 256) {
        unsigned w = (xw[i] & 0xFFFFu) << 16;
        float av = fabsf(__builtin_bit_cast(float, w));
        if (av > 0.0009f && av < 64.0f) ok++;
    }
    for (int i = threadIdx.x; i < STRIPES * 2 * HDIM; i += 256) gpart[i] = 0.f;
    if (lo) atomicAdd(&nzhi, lo);
    if (ok) atomicAdd(&okbf, ok);
    __syncthreads();
    if (threadIdx.x == 0) {
        flags[0] = (nzhi == 0) ? 1 : 0;
        flags[1] = (okbf < 512) ? 1 : 0;
    }
}

// convert ei (2E) + batch (N) to int32, and count in-degrees from cols on the fly
__global__ void conv_all_idx(const int* __restrict__ ei, const int* __restrict__ batch,
                             int* __restrict__ ei32, int* __restrict__ batch32,
                             int* __restrict__ cnt, int e2, int n,
                             const int* __restrict__ flags) {
    int i = blockIdx.x * blockDim.x + threadIdx.x;
    int i64 = flags[0];
    if (i < e2) {
        int v = i64 ? (int)((const long long*)ei)[i] : ei[i];
        ei32[i] = v;
        if (i >= e2 / 2) atomicAdd(&cnt[v], 1);   // cols half
    } else if (i < e2 + n) {
        int j = i - e2;
        batch32[j] = i64 ? (int)((const long long*)batch)[j] : batch[j];
    }
}

// convert + transpose all weights and the final bias in one launch
__global__ void wt_conv_all(const void* __restrict__ W1, const void* __restrict__ W2,
                            const void* __restrict__ Wf, const void* __restrict__ bf_,
                            bf16* __restrict__ W1T, bf16* __restrict__ W2T,
                            bf16* __restrict__ WfT, bf16* __restrict__ bfbf,
                            const int* __restrict__ flags) {
    const int S1 = 128 * 512, S2 = 512 * 512, S3 = 512 * 256;
    int idx = blockIdx.x * 256 + threadIdx.x;
    bool f32 = flags[1] != 0;
    if (idx < S1) {
        int nn = idx / 128, k = idx - nn * 128;   // K=128, Nn=512
        float v = f32 ? ((const float*)W1)[(size_t)k * 512 + nn]
                      : __bfloat162float(((const bf16*)W1)[(size_t)k * 512 + nn]);
        W1T[idx] = __float2bfloat16(v);
    } else if (idx < S1 + S2) {
        int t = idx - S1;
        int nn = t / 512, k = t - nn * 512;       // K=512, Nn=512
        float v = f32 ? ((const float*)W2)[(size_t)k * 512 + nn]
                      : __bfloat162float(((const bf16*)W2)[(size_t)k * 512 + nn]);
        W2T[t] = __float2bfloat16(v);
    } else if (idx < S1 + S2 + S3) {
        int t = idx - S1 - S2;
        int nn = t / 512, k = t - nn * 512;       // K=512, Nn=256
        float v = f32 ? ((const float*)Wf)[(size_t)k * 256 + nn]
                      : __bfloat162float(((const bf16*)Wf)[(size_t)k * 256 + nn]);
        WfT[t] = __float2bfloat16(v);
    } else if (idx < S1 + S2 + S3 + 256) {
        int t = idx - S1 - S2 - S3;
        float v = f32 ? ((const float*)bf_)[t]
                      : __bfloat162float(((const bf16*)bf_)[t]);
        bfbf[t] = __float2bfloat16(v);
    }
}

__global__ void finalize_deg(const int* __restrict__ cnt, float* __restrict__ dinv,
                             float* __restrict__ selfw, int n) {
    int i = blockIdx.x * blockDim.x + threadIdx.x;
    if (i < n) {
        float d = (float)cnt[i] + 2.0f;
        dinv[i] = rsqrtf(d);
        selfw[i] = 2.0f / d;
    }
}

// ---------------- parallel exclusive scan (3 kernels, 512 elems/block) -----------
__global__ __launch_bounds__(256) void scan_part(
    const int* __restrict__ counts, int* __restrict__ offsets,
    int* __restrict__ bsum, int n)
{
    __shared__ int s[512];
    int b = blockIdx.x;
    int base = b * 512;
    int t = threadIdx.x;
    s[t]       = (base + t       < n) ? counts[base + t]       : 0;
    s[t + 256] = (base + t + 256 < n) ? counts[base + t + 256] : 0;

    int offset = 1;
    for (int d = 256; d > 0; d >>= 1) {
        __syncthreads();
        if (t < d) {
            int ai = offset * (2 * t + 1) - 1;
            int bi = offset * (2 * t + 2) - 1;
            s[bi] += s[ai];
        }
        offset <<= 1;
    }
    __syncthreads();
    if (t == 0) { bsum[b] = s[511]; s[511] = 0; }
    for (int d = 1; d < 512; d <<= 1) {
        offset >>= 1;
        __syncthreads();
        if (t < d) {
            int ai = offset * (2 * t + 1) - 1;
            int bi = offset * (2 * t + 2) - 1;
            int tmp = s[ai]; s[ai] = s[bi]; s[bi] += tmp;
        }
    }
    __syncthreads();
    if (base + t < n)       offsets[base + t]       = s[t];
    if (base + t + 256 < n) offsets[base + t + 256] = s[t + 256];
}

__global__ __launch_bounds__(1024) void scan_tops(int* __restrict__ bsum, int nb) {
    __shared__ int s[1024];
    int t = threadIdx.x;
    s[t] = (t < nb) ? bsum[t] : 0;
    __syncthreads();
    for (int off = 1; off < 1024; off <<= 1) {
        int v = (t >= off) ? s[t - off] : 0;
        __syncthreads();
        s[t] += v;
        __syncthreads();
    }
    if (t < nb) bsum[t] = (t == 0) ? 0 : s[t - 1];   // exclusive
}

__global__ __launch_bounds__(256) void scan_add(
    int* __restrict__ offsets, const int* __restrict__ bsum, int n, int e)
{
    int b = blockIdx.x;
    int base = b * 512;
    int add = bsum[b];
    int t = threadIdx.x;
    if (base + t < n)       offsets[base + t]       += add;
    if (base + t + 256 < n) offsets[base + t + 256] += add;
    if (b == 0 && t == 0) offsets[n] = e;
}

// scatter edges into CSR order + precompute per-edge norm dinv[d]*dinv[s]
__global__ void scatter_edges(const int* __restrict__ rows, const int* __restrict__ cols,
                              const int* __restrict__ offsets, int* __restrict__ cursor,
                              const float* __restrict__ dinv,
                              int* __restrict__ src, float* __restrict__ ecn, int e)
{
    int i = blockIdx.x * blockDim.x + threadIdx.x;
    if (i < e) {
        int d = cols[i];
        int r = rows[i];
        int pos = offsets[d] + atomicAdd(&cursor[d], 1);
        src[pos] = r;
        ecn[pos] = dinv[d] * dinv[r];
    }
}

// -- m97-style GEMM, 128m x 256n block (wave 64m x 128n), BK=32, XOR swizzle -------
// 32 MFMA/wave between barriers (2x R17) to raise compute/latency ratio.
// XCD-swizzled 1D grid; NBN = N/256 n-blocks. 3 blocks/CU (reg cap 170).
template<bool STATS>
__global__ __launch_bounds__(256, 3) void gemm_m97(
    const bf16* __restrict__ A, const bf16* __restrict__ BT,
    void* __restrict__ C, const bf16* __restrict__ bias,
    int M, int K, int N, const int* __restrict__ cf32,
    float* __restrict__ gpart, int MB)
{
    __shared__ bf16 As[128 * 32];
    __shared__ bf16 Bs[256 * 32];
    __shared__ float ssum[STATS ? 256 : 1];
    __shared__ float ssq[STATS ? 256 : 1];

    int NBN = N >> 8;                       // 256-wide n-blocks
    int id = blockIdx.x;
    int grp = id / (8 * NBN);
    int loc = id - grp * 8 * NBN;
    int mi = loc & 7;
    int nblk = loc >> 3;
    int mblk = grp * 8 + mi;
    if (mblk >= MB) return;

    int tid = threadIdx.x;
    int wave = tid >> 6, lane = tid & 63, q = lane >> 4, r = lane & 15;
    int wm = (wave >> 1) * 64, wn = (wave & 1) * 128;
    int m0 = mblk * 128, n0 = nblk * 256;
    bool c32 = cf32 && *cf32;

    if constexpr (STATS) { ssum[tid] = 0.f; ssq[tid] = 0.f; }

    int lrow = lane >> 2;
    int lcol = (((lane & 3) ^ ((lane >> 3) & 3)) * 8);   // XOR-swizzled source chunk
    int aoff = (q ^ ((r >> 1) & 3)) * 8;                 // fragment-read swizzle

    f32x4 acc[4][8];
#pragma unroll
    for (int mi2 = 0; mi2 < 4; mi2++)
#pragma unroll
        for (int ni = 0; ni < 8; ni++)
            acc[mi2][ni] = {0.f, 0.f, 0.f, 0.f};

    for (int k0 = 0; k0 < K; k0 += 32) {
#pragma unroll
        for (int i = 0; i < 2; i++) {        // A: 8 chunks, 2 per wave
            int c = wave * 2 + i;
            const bf16* ga = A + (size_t)(m0 + c * 16 + lrow) * K + k0 + lcol;
            __builtin_amdgcn_global_load_lds(
                (const __attribute__((address_space(1))) unsigned*)ga,
                (__attribute__((address_space(3))) unsigned*)(As + c * 512), 16, 0, 0);
        }
#pragma unroll
        for (int i = 0; i < 4; i++) {        // B: 16 chunks, 4 per wave
            int c = wave * 4 + i;
            const bf16* gb = BT + (size_t)(n0 + c * 16 + lrow) * K + k0 + lcol;
            __builtin_amdgcn_global_load_lds(
                (const __attribute__((address_space(1))) unsigned*)gb,
                (__attribute__((address_space(3))) unsigned*)(Bs + c * 512), 16, 0, 0);
        }
        __syncthreads();

        short8 a[4];
#pragma unroll
        for (int mi2 = 0; mi2 < 4; mi2++) a[mi2] = *(const short8*)&As[(wm + mi2 * 16 + r) * 32 + aoff];
#pragma unroll
        for (int ni = 0; ni < 8; ni++) {
            short8 b = *(const short8*)&Bs[(wn + ni * 16 + r) * 32 + aoff];
#pragma unroll
            for (int mi2 = 0; mi2 < 4; mi2++)
                acc[mi2][ni] = __builtin_amdgcn_mfma_f32_16x16x32_bf16(a[mi2], b, acc[mi2][ni], 0, 0, 0);
        }
        __syncthreads();
    }

#pragma unroll
    for (int mi2 = 0; mi2 < 4; mi2++) {
#pragma unroll
        for (int ni = 0; ni < 8; ni++) {
            int gn = n0 + wn + ni * 16 + r;
            float bv = bias ? __bfloat162float(bias[gn]) : 0.f;
#pragma unroll
            for (int reg = 0; reg < 4; reg++) {
                int gm = m0 + wm + mi2 * 16 + q * 4 + reg;
                if (gm < M) {
                    float val = acc[mi2][ni][reg] + bv;
                    if (c32) ((float*)C)[(size_t)gm * N + gn] = val;
                    else     ((bf16*)C)[(size_t)gm * N + gn] = __float2bfloat16(val);
                }
            }
        }
    }

    if constexpr (STATS) {
#pragma unroll
        for (int ni = 0; ni < 8; ni++) {
            float cs = 0.f, cq = 0.f;
#pragma unroll
            for (int mi2 = 0; mi2 < 4; mi2++)
#pragma unroll
                for (int reg = 0; reg < 4; reg++) {
                    int gm = m0 + wm + mi2 * 16 + q * 4 + reg;
                    if (gm < M) {
                        float v = acc[mi2][ni][reg];
                        cs += v; cq += v * v;
                    }
                }
            int c = wn + ni * 16 + r;
            atomicAdd(&ssum[c], cs);
            atomicAdd(&ssq[c], cq);
        }
        __syncthreads();
        {
            float* base = gpart + (size_t)(mblk & (STRIPES - 1)) * 2 * HDIM;
            atomicAdd(&base[n0 + tid], ssum[tid]);
            atomicAdd(&base[HDIM + n0 + tid], ssq[tid]);
        }
    }
}

// ----- persistent CSR aggregation, 128-dim input, edge-loop unroll x2 -------------
__global__ __launch_bounds__(256) void agg_csr_din(
    const void* __restrict__ x, const int* __restrict__ offsets,
    const int* __restrict__ src, const float* __restrict__ ecn,
    const float* __restrict__ selfw, bf16* __restrict__ out,
    int n, const int* __restrict__ flags)
{
    int wave = threadIdx.x >> 6, lane = threadIdx.x & 63;
    int gw = blockIdx.x * 4 + wave;
    int nw = gridDim.x * 4;
    bool f32 = flags[1] != 0;

    for (int dst = gw; dst < n; dst += nw) {
        int s0 = offsets[dst], s1 = offsets[dst + 1];
        float sw = selfw[dst];
        float a0, a1;
        if (f32) {
            float2 v = ((const float2*)x)[(size_t)dst * 64 + lane];
            a0 = sw * v.x; a1 = sw * v.y;
        } else {
            unsigned u = ((const unsigned*)x)[(size_t)dst * 64 + lane];
            a0 = sw * bf2f((short)(u & 0xFFFF)); a1 = sw * bf2f((short)(u >> 16));
        }
        int p = s0;
        for (; p + 1 < s1; p += 2) {
            int sr0 = src[p], sr1 = src[p + 1];
            float n0 = ecn[p], n1 = ecn[p + 1];
            if (f32) {
                float2 v0 = ((const float2*)x)[(size_t)sr0 * 64 + lane];
                float2 v1 = ((const float2*)x)[(size_t)sr1 * 64 + lane];
                a0 += n0 * v0.x + n1 * v1.x;
                a1 += n0 * v0.y + n1 * v1.y;
            } else {
                unsigned u0 = ((const unsigned*)x)[(size_t)sr0 * 64 + lane];
                unsigned u1 = ((const unsigned*)x)[(size_t)sr1 * 64 + lane];
                a0 += n0 * bf2f((short)(u0 & 0xFFFF)) + n1 * bf2f((short)(u1 & 0xFFFF));
                a1 += n0 * bf2f((short)(u0 >> 16))    + n1 * bf2f((short)(u1 >> 16));
            }
        }
        if (p < s1) {
            int sr0 = src[p];
            float n0 = ecn[p];
            if (f32) {
                float2 v0 = ((const float2*)x)[(size_t)sr0 * 64 + lane];
                a0 += n0 * v0.x; a1 += n0 * v0.y;
            } else {
                unsigned u0 = ((const unsigned*)x)[(size_t)sr0 * 64 + lane];
                a0 += n0 * bf2f((short)(u0 & 0xFFFF)); a1 += n0 * bf2f((short)(u0 >> 16));
            }
        }
        ((unsigned*)out)[(size_t)dst * 64 + lane] =
            (unsigned)f2bfbits(a0) | ((unsigned)f2bfbits(a1) << 16);
    }
}

// -- persistent CSR aggregation (512-dim) with fused BN-affine+leaky, unroll x2 ----
__global__ __launch_bounds__(256) void agg_csr_bn(
    const bf16* __restrict__ h, const int* __restrict__ offsets,
    const int* __restrict__ src, const float* __restrict__ ecn,
    const float* __restrict__ selfw,
    const float* __restrict__ scale, const float* __restrict__ shift,
    bf16* __restrict__ y, int n)
{
    int wave = threadIdx.x >> 6, lane = threadIdx.x & 63;
    int f0 = lane * 8;
    int gw = blockIdx.x * 4 + wave;
    int nw = gridDim.x * 4;

    float sc[8], sh[8];
#pragma unroll
    for (int j = 0; j < 8; j++) { sc[j] = scale[f0 + j]; sh[j] = shift[f0 + j]; }

    for (int dst = gw; dst < n; dst += nw) {
        int s0 = offsets[dst], s1 = offsets[dst + 1];
        float sw = selfw[dst];
        short8 hv = *(const short8*)(h + (size_t)dst * HDIM + f0);
        float acc[8];
#pragma unroll
        for (int j = 0; j < 8; j++) {
            float t = sc[j] * bf2f(hv[j]) + sh[j];
            t = t > 0.f ? t : SLOPE * t;
            acc[j] = sw * t;
        }
        int p = s0;
        for (; p + 1 < s1; p += 2) {
            int sr0 = src[p], sr1 = src[p + 1];
            float n0 = ecn[p], n1 = ecn[p + 1];
            short8 v0 = *(const short8*)(h + (size_t)sr0 * HDIM + f0);
            short8 v1 = *(const short8*)(h + (size_t)sr1 * HDIM + f0);
#pragma unroll
            for (int j = 0; j < 8; j++) {
                float t0 = sc[j] * bf2f(v0[j]) + sh[j];
                t0 = t0 > 0.f ? t0 : SLOPE * t0;
                float t1 = sc[j] * bf2f(v1[j]) + sh[j];
                t1 = t1 > 0.f ? t1 : SLOPE * t1;
                acc[j] += n0 * t0 + n1 * t1;
            }
        }
        if (p < s1) {
            int sr0 = src[p];
            float n0 = ecn[p];
            short8 v0 = *(const short8*)(h + (size_t)sr0 * HDIM + f0);
#pragma unroll
            for (int j = 0; j < 8; j++) {
                float t0 = sc[j] * bf2f(v0[j]) + sh[j];
                t0 = t0 > 0.f ? t0 : SLOPE * t0;
                acc[j] += n0 * t0;
            }
        }
        short8 o;
#pragma unroll
        for (int j = 0; j < 8; j++) ((bf16*)&o)[j] = __float2bfloat16(acc[j]);
        *(short8*)(y + (size_t)dst * HDIM + f0) = o;
    }
}

// ------ BN coeffs from striped partials; re-zeros gpart for the next layer --------
__global__ void bn_final(float* __restrict__ gpart,
                         const void* __restrict__ gamma, const void* __restrict__ beta,
                         float* __restrict__ scale, float* __restrict__ shift,
                         float invN, const int* __restrict__ flags)
{
    int f = threadIdx.x;
    float s = 0.f, q = 0.f;
#pragma unroll
    for (int k = 0; k < STRIPES; k++) {
        s += gpart[(size_t)k * 2 * HDIM + f];
        q += gpart[(size_t)k * 2 * HDIM + HDIM + f];
        gpart[(size_t)k * 2 * HDIM + f] = 0.f;
        gpart[(size_t)k * 2 * HDIM + HDIM + f] = 0.f;
    }
    float g = flags[1] ? ((const float*)gamma)[f]
                       : __bfloat162float(((const bf16*)gamma)[f]);
    float b = flags[1] ? ((const float*)beta)[f]
                       : __bfloat162float(((const bf16*)beta)[f]);
    float mu = s * invN;
    float var = fmaxf(q * invN - mu * mu, 0.f);
    float inv = rsqrtf(var + BN_EPS);
    float sc = g * inv;
    scale[f] = sc;
    shift[f] = b - mu * sc;
}

// ---------------- pooling with fused BN+LeakyReLU (monotone) ----------------------
__global__ __launch_bounds__(512) void pool_fused(
    const bf16* __restrict__ y, const int* __restrict__ batch,
    const float* __restrict__ scale, const float* __restrict__ shift,
    bf16* __restrict__ pooled, int n)
{
    int g = blockIdx.x;
    int f = threadIdx.x;
    int lo = 0, hi = n;
    while (lo < hi) { int mid = (lo + hi) >> 1; if (batch[mid] < g) lo = mid + 1; else hi = mid; }
    int s = lo;
    hi = n;
    while (lo < hi) { int mid = (lo + hi) >> 1; if (batch[mid] <= g) lo = mid + 1; else hi = mid; }
    int e = lo;
    float mx = -3.0e38f, mn = 3.0e38f;
    for (int rr = s; rr < e; rr++) {
        float v = bf2f(__builtin_bit_cast(short, y[(size_t)rr * HDIM + f]));
        mx = fmaxf(mx, v); mn = fminf(mn, v);
    }
    float outv = 0.f;
    if (s < e) {
        float sc = scale[f];
        float t = sc * (sc >= 0.f ? mx : mn) + shift[f];
        outv = t > 0.f ? t : SLOPE * t;
    }
    pooled[(size_t)g * HDIM + f] = __float2bfloat16(outv);
}

// ---------------- orchestration --------------------------------------------------
extern "C" void kernel_launch(void* const* d_in, const int* in_sizes, int n_in,
                              void* d_out, int out_size, void* d_ws, size_t ws_size,
                              hipStream_t stream)
{
    const void* x     = d_in[0];
    const int*  ei    = (const int*)d_in[1];
    const int*  batch = (const int*)d_in[2];
    // d_in[4]=b1, d_in[8]=b2 cancel in training-mode BatchNorm — unused.

    const int N   = in_sizes[2];
    const int E   = in_sizes[1] / 2;
    const int DIN = 128;
    const int OUT = 256;
    const int G   = out_size / OUT;
    const int Mp  = (N + 127) & ~127;
    const int MB  = Mp / 128;
    const int MB8 = (MB + 7) & ~7;

    // workspace carve — ~237 MB
    char* p = (char*)d_ws;
    bf16* B1     = (bf16*)p;  p += (size_t)Mp * HDIM * sizeof(bf16);
    bf16* B2     = (bf16*)p;  p += (size_t)Mp * HDIM * sizeof(bf16);
    bf16* Q      = (bf16*)p;  p += (size_t)Mp * DIN * sizeof(bf16);
    bf16* W1T    = (bf16*)p;  p += (size_t)HDIM * DIN * sizeof(bf16);
    bf16* W2T    = (bf16*)p;  p += (size_t)HDIM * HDIM * sizeof(bf16);
    bf16* WfT    = (bf16*)p;  p += (size_t)OUT * HDIM * sizeof(bf16);
    bf16* bfbf   = (bf16*)p;  p += 512 * sizeof(bf16);
    int* ei32    = (int*)p;   p += (size_t)2 * E * sizeof(int);
    int* batch32 = (int*)p;   p += (size_t)N * sizeof(int);
    float* dinv  = (float*)p; p += (size_t)N * sizeof(float);
    float* selfw = (float*)p; p += (size_t)N * sizeof(float);
    int* offsets = (int*)p;   p += (size_t)(N + 4) * sizeof(int);
    int* cursor  = (int*)p;   p += (size_t)N * sizeof(int);
    int* srcarr  = (int*)p;   p += (size_t)E * sizeof(int);
    float* ecn   = (float*)p; p += (size_t)E * sizeof(float);
    int* bsum    = (int*)p;   p += 1024 * sizeof(int);
    float* gpart = (float*)p; p += (size_t)STRIPES * 2 * HDIM * sizeof(float);
    float* sc1   = (float*)p; p += HDIM * sizeof(float);
    float* sh1   = (float*)p; p += HDIM * sizeof(float);
    float* sc2   = (float*)p; p += HDIM * sizeof(float);
    float* sh2   = (float*)p; p += HDIM * sizeof(float);
    int* flags   = (int*)p;   p += 4 * sizeof(int);

    // ---- detection (+gpart zero) + fused conversions + degree count ----
    detect_types<<<1, 256, 0, stream>>>(ei, (const unsigned*)x, flags, gpart);
    hipMemsetAsync(cursor, 0, (size_t)N * sizeof(int), stream);
    conv_all_idx<<<(2 * E + N + 255) / 256, 256, 0, stream>>>(
        ei, batch, ei32, batch32, cursor, 2 * E, N, flags);
    wt_conv_all<<<(128 * 512 + 512 * 512 + 512 * 256 + 256 + 255) / 256, 256, 0, stream>>>(
        d_in[3], d_in[7], d_in[11], d_in[12], W1T, W2T, WfT, bfbf, flags);

    const int* rows = ei32;
    const int* cols = ei32 + E;

    // ---- CSR + degrees + per-edge norms ----
    finalize_deg<<<(N + 255) / 256, 256, 0, stream>>>(cursor, dinv, selfw, N);
    int nb = (N + 511) / 512;
    scan_part<<<nb, 256, 0, stream>>>(cursor, offsets, bsum, N);
    scan_tops<<<1, 1024, 0, stream>>>(bsum, nb);
    scan_add<<<nb, 256, 0, stream>>>(offsets, bsum, N, E);
    hipMemsetAsync(cursor, 0, (size_t)N * sizeof(int), stream);
    scatter_edges<<<(E + 255) / 256, 256, 0, stream>>>(rows, cols, offsets, cursor,
                                                       dinv, srcarr, ecn, E);

    int gemm_blocks = MB8 * (HDIM / 256);   // 256-wide n-blocks

    // ---- layer 1: aggregate x (agg is linear), GEMM w/ fused stats ----
    agg_csr_din<<<2048, 256, 0, stream>>>(x, offsets, srcarr, ecn, selfw, Q, N, flags);
    gemm_m97<true><<<gemm_blocks, 256, 0, stream>>>(
        Q, W1T, B2, nullptr, N, DIN, HDIM, nullptr, gpart, MB);
    bn_final<<<1, HDIM, 0, stream>>>(gpart, d_in[5], d_in[6], sc1, sh1, 1.0f / N, flags);

    // ---- layer 2: aggregate RAW conv1 output w/ fused BN+leaky, GEMM w/ stats ----
    agg_csr_bn<<<2048, 256, 0, stream>>>(B2, offsets, srcarr, ecn, selfw, sc1, sh1, B1, N);
    gemm_m97<true><<<gemm_blocks, 256, 0, stream>>>(
        B1, W2T, B2, nullptr, N, HDIM, HDIM, nullptr, gpart, MB);
    bn_final<<<1, HDIM, 0, stream>>>(gpart, d_in[9], d_in[10], sc2, sh2, 1.0f / N, flags);

    // ---- pool (fused BN+leaky, monotone) + head GEMM ----
    pool_fused<<<G, HDIM, 0, stream>>>(B2, batch32, sc2, sh2, Q, N);
    gemm_m97<false><<<(G / 128) * (OUT / 256), 256, 0, stream>>>(
        Q, WfT, d_out, bfbf, G, HDIM, OUT, flags + 1, nullptr, G / 128);
}

// Round 19
// 521.653 us; speedup vs baseline: 1.1297x; 1.1297x over previous
//
#include <hip/hip_runtime.h>
#include <hip/hip_bf16.h>

typedef __hip_bfloat16 bf16;
typedef __attribute__((ext_vector_type(8))) short short8;
typedef __attribute__((ext_vector_type(4))) float f32x4;

#define HDIM 512
#define SLOPE 0.01f
#define BN_EPS 1e-5f
#define STRIPES 8

__device__ inline float bf2f(short s) {
    unsigned u = ((unsigned)(unsigned short)s) << 16;
    return __builtin_bit_cast(float, u);
}
__device__ inline unsigned short f2bfbits(float v) {
    bf16 h = __float2bfloat16(v);
    return (unsigned short)__builtin_bit_cast(short, h);
}

// ---------------- dtype detection + gpart zero-init ----------------
__global__ void detect_types(const int* __restrict__ ei, const unsigned* __restrict__ xw,
                             int* __restrict__ flags, float* __restrict__ gpart) {
    __shared__ int nzhi, okbf;
    if (threadIdx.x == 0) { nzhi = 0; okbf = 0; }
    __syncthreads();
    int lo = 0, ok = 0;
    for (int i = threadIdx.x; i < 2048; i += 256)
        if (ei[2 * i + 1] != 0) lo++;
    for (int i = threadIdx.x; i < 1024; i += 256) {
        unsigned w = (xw[i] & 0xFFFFu) << 16;
        float av = fabsf(__builtin_bit_cast(float, w));
        if (av > 0.0009f && av < 64.0f) ok++;
    }
    for (int i = threadIdx.x; i < STRIPES * 2 * HDIM; i += 256) gpart[i] = 0.f;
    if (lo) atomicAdd(&nzhi, lo);
    if (ok) atomicAdd(&okbf, ok);
    __syncthreads();
    if (threadIdx.x == 0) {
        flags[0] = (nzhi == 0) ? 1 : 0;
        flags[1] = (okbf < 512) ? 1 : 0;
    }
}

// convert ei (2E) + batch (N) to int32, and count in-degrees from cols on the fly
__global__ void conv_all_idx(const int* __restrict__ ei, const int* __restrict__ batch,
                             int* __restrict__ ei32, int* __restrict__ batch32,
                             int* __restrict__ cnt, int e2, int n,
                             const int* __restrict__ flags) {
    int i = blockIdx.x * blockDim.x + threadIdx.x;
    int i64 = flags[0];
    if (i < e2) {
        int v = i64 ? (int)((const long long*)ei)[i] : ei[i];
        ei32[i] = v;
        if (i >= e2 / 2) atomicAdd(&cnt[v], 1);   // cols half
    } else if (i < e2 + n) {
        int j = i - e2;
        batch32[j] = i64 ? (int)((const long long*)batch)[j] : batch[j];
    }
}

// convert + transpose all weights and the final bias in one launch
__global__ void wt_conv_all(const void* __restrict__ W1, const void* __restrict__ W2,
                            const void* __restrict__ Wf, const void* __restrict__ bf_,
                            bf16* __restrict__ W1T, bf16* __restrict__ W2T,
                            bf16* __restrict__ WfT, bf16* __restrict__ bfbf,
                            const int* __restrict__ flags) {
    const int S1 = 128 * 512, S2 = 512 * 512, S3 = 512 * 256;
    int idx = blockIdx.x * 256 + threadIdx.x;
    bool f32 = flags[1] != 0;
    if (idx < S1) {
        int nn = idx / 128, k = idx - nn * 128;   // K=128, Nn=512
        float v = f32 ? ((const float*)W1)[(size_t)k * 512 + nn]
                      : __bfloat162float(((const bf16*)W1)[(size_t)k * 512 + nn]);
        W1T[idx] = __float2bfloat16(v);
    } else if (idx < S1 + S2) {
        int t = idx - S1;
        int nn = t / 512, k = t - nn * 512;       // K=512, Nn=512
        float v = f32 ? ((const float*)W2)[(size_t)k * 512 + nn]
                      : __bfloat162float(((const bf16*)W2)[(size_t)k * 512 + nn]);
        W2T[t] = __float2bfloat16(v);
    } else if (idx < S1 + S2 + S3) {
        int t = idx - S1 - S2;
        int nn = t / 512, k = t - nn * 512;       // K=512, Nn=256
        float v = f32 ? ((const float*)Wf)[(size_t)k * 256 + nn]
                      : __bfloat162float(((const bf16*)Wf)[(size_t)k * 256 + nn]);
        WfT[t] = __float2bfloat16(v);
    } else if (idx < S1 + S2 + S3 + 256) {
        int t = idx - S1 - S2 - S3;
        float v = f32 ? ((const float*)bf_)[t]
                      : __bfloat162float(((const bf16*)bf_)[t]);
        bfbf[t] = __float2bfloat16(v);
    }
}

__global__ void finalize_deg(const int* __restrict__ cnt, float* __restrict__ dinv,
                             float* __restrict__ selfw, int n) {
    int i = blockIdx.x * blockDim.x + threadIdx.x;
    if (i < n) {
        float d = (float)cnt[i] + 2.0f;
        dinv[i] = rsqrtf(d);
        selfw[i] = 2.0f / d;
    }
}

// ---------------- parallel exclusive scan (3 kernels, 512 elems/block) -----------
__global__ __launch_bounds__(256) void scan_part(
    const int* __restrict__ counts, int* __restrict__ offsets,
    int* __restrict__ bsum, int n)
{
    __shared__ int s[512];
    int b = blockIdx.x;
    int base = b * 512;
    int t = threadIdx.x;
    s[t]       = (base + t       < n) ? counts[base + t]       : 0;
    s[t + 256] = (base + t + 256 < n) ? counts[base + t + 256] : 0;

    int offset = 1;
    for (int d = 256; d > 0; d >>= 1) {
        __syncthreads();
        if (t < d) {
            int ai = offset * (2 * t + 1) - 1;
            int bi = offset * (2 * t + 2) - 1;
            s[bi] += s[ai];
        }
        offset <<= 1;
    }
    __syncthreads();
    if (t == 0) { bsum[b] = s[511]; s[511] = 0; }
    for (int d = 1; d < 512; d <<= 1) {
        offset >>= 1;
        __syncthreads();
        if (t < d) {
            int ai = offset * (2 * t + 1) - 1;
            int bi = offset * (2 * t + 2) - 1;
            int tmp = s[ai]; s[ai] = s[bi]; s[bi] += tmp;
        }
    }
    __syncthreads();
    if (base + t < n)       offsets[base + t]       = s[t];
    if (base + t + 256 < n) offsets[base + t + 256] = s[t + 256];
}

__global__ __launch_bounds__(1024) void scan_tops(int* __restrict__ bsum, int nb) {
    __shared__ int s[1024];
    int t = threadIdx.x;
    s[t] = (t < nb) ? bsum[t] : 0;
    __syncthreads();
    for (int off = 1; off < 1024; off <<= 1) {
        int v = (t >= off) ? s[t - off] : 0;
        __syncthreads();
        s[t] += v;
        __syncthreads();
    }
    if (t < nb) bsum[t] = (t == 0) ? 0 : s[t - 1];   // exclusive
}

__global__ __launch_bounds__(256) void scan_add(
    int* __restrict__ offsets, const int* __restrict__ bsum, int n, int e)
{
    int b = blockIdx.x;
    int base = b * 512;
    int add = bsum[b];
    int t = threadIdx.x;
    if (base + t < n)       offsets[base + t]       += add;
    if (base + t + 256 < n) offsets[base + t + 256] += add;
    if (b == 0 && t == 0) offsets[n] = e;
}

// scatter edges into CSR order + precompute per-edge norm dinv[d]*dinv[s]
__global__ void scatter_edges(const int* __restrict__ rows, const int* __restrict__ cols,
                              const int* __restrict__ offsets, int* __restrict__ cursor,
                              const float* __restrict__ dinv,
                              int* __restrict__ src, float* __restrict__ ecn, int e)
{
    int i = blockIdx.x * blockDim.x + threadIdx.x;
    if (i < e) {
        int d = cols[i];
        int r = rows[i];
        int pos = offsets[d] + atomicAdd(&cursor[d], 1);
        src[pos] = r;
        ecn[pos] = dinv[d] * dinv[r];
    }
}

// ------ m97-style GEMM, BK=32, XCD-swizzled grid, 4 waves/EU cap, LDS XOR-swizzle -
// (R17 configuration — best measured. Tile-space alternatives BK=64 and 128x256
//  both regressed: barrier overlap via occupancy beats per-barrier amortization.)
template<bool STATS>
__global__ __launch_bounds__(256, 4) void gemm_m97(
    const bf16* __restrict__ A, const bf16* __restrict__ BT,
    void* __restrict__ C, const bf16* __restrict__ bias,
    int M, int K, int N, const int* __restrict__ cf32,
    float* __restrict__ gpart, int MB)
{
    __shared__ bf16 As[128 * 32];
    __shared__ bf16 Bs[128 * 32];
    __shared__ float ssum[STATS ? 128 : 1];
    __shared__ float ssq[STATS ? 128 : 1];

    int NBN = N >> 7;
    int id = blockIdx.x;
    int grp = id / (8 * NBN);
    int loc = id - grp * 8 * NBN;
    int mi = loc & 7;
    int nblk = loc >> 3;
    int mblk = grp * 8 + mi;
    if (mblk >= MB) return;

    int tid = threadIdx.x;
    int wave = tid >> 6, lane = tid & 63, q = lane >> 4, r = lane & 15;
    int wm = (wave >> 1) * 64, wn = (wave & 1) * 64;
    int m0 = mblk * 128, n0 = nblk * 128;
    bool c32 = cf32 && *cf32;

    if constexpr (STATS) {
        if (tid < 128) { ssum[tid] = 0.f; ssq[tid] = 0.f; }
    }

    int lrow = lane >> 2;
    int lcol = (((lane & 3) ^ ((lane >> 3) & 3)) * 8);   // XOR-swizzled source chunk
    int aoff = (q ^ ((r >> 1) & 3)) * 8;                 // fragment-read swizzle

    f32x4 acc[4][4];
#pragma unroll
    for (int mi2 = 0; mi2 < 4; mi2++)
#pragma unroll
        for (int ni = 0; ni < 4; ni++)
            acc[mi2][ni] = {0.f, 0.f, 0.f, 0.f};

    for (int k0 = 0; k0 < K; k0 += 32) {
#pragma unroll
        for (int i = 0; i < 2; i++) {
            int c = wave * 2 + i;
            const bf16* ga = A  + (size_t)(m0 + c * 16 + lrow) * K + k0 + lcol;
            const bf16* gb = BT + (size_t)(n0 + c * 16 + lrow) * K + k0 + lcol;
            __builtin_amdgcn_global_load_lds(
                (const __attribute__((address_space(1))) unsigned*)ga,
                (__attribute__((address_space(3))) unsigned*)(As + c * 512), 16, 0, 0);
            __builtin_amdgcn_global_load_lds(
                (const __attribute__((address_space(1))) unsigned*)gb,
                (__attribute__((address_space(3))) unsigned*)(Bs + c * 512), 16, 0, 0);
        }
        __syncthreads();

        short8 a[4], b[4];
#pragma unroll
        for (int mi2 = 0; mi2 < 4; mi2++) a[mi2] = *(const short8*)&As[(wm + mi2 * 16 + r) * 32 + aoff];
#pragma unroll
        for (int ni = 0; ni < 4; ni++) b[ni] = *(const short8*)&Bs[(wn + ni * 16 + r) * 32 + aoff];
#pragma unroll
        for (int mi2 = 0; mi2 < 4; mi2++)
#pragma unroll
            for (int ni = 0; ni < 4; ni++)
                acc[mi2][ni] = __builtin_amdgcn_mfma_f32_16x16x32_bf16(a[mi2], b[ni], acc[mi2][ni], 0, 0, 0);
        __syncthreads();
    }

#pragma unroll
    for (int mi2 = 0; mi2 < 4; mi2++) {
#pragma unroll
        for (int ni = 0; ni < 4; ni++) {
            int gn = n0 + wn + ni * 16 + r;
            float bv = bias ? __bfloat162float(bias[gn]) : 0.f;
#pragma unroll
            for (int reg = 0; reg < 4; reg++) {
                int gm = m0 + wm + mi2 * 16 + q * 4 + reg;
                if (gm < M) {
                    float val = acc[mi2][ni][reg] + bv;
                    if (c32) ((float*)C)[(size_t)gm * N + gn] = val;
                    else     ((bf16*)C)[(size_t)gm * N + gn] = __float2bfloat16(val);
                }
            }
        }
    }

    if constexpr (STATS) {
#pragma unroll
        for (int ni = 0; ni < 4; ni++) {
            float cs = 0.f, cq = 0.f;
#pragma unroll
            for (int mi2 = 0; mi2 < 4; mi2++)
#pragma unroll
                for (int reg = 0; reg < 4; reg++) {
                    int gm = m0 + wm + mi2 * 16 + q * 4 + reg;
                    if (gm < M) {
                        float v = acc[mi2][ni][reg];
                        cs += v; cq += v * v;
                    }
                }
            int c = wn + ni * 16 + r;
            atomicAdd(&ssum[c], cs);
            atomicAdd(&ssq[c], cq);
        }
        __syncthreads();
        if (tid < 128) {
            float* base = gpart + (size_t)(mblk & (STRIPES - 1)) * 2 * HDIM;
            atomicAdd(&base[n0 + tid], ssum[tid]);
            atomicAdd(&base[HDIM + n0 + tid], ssq[tid]);
        }
    }
}

// ----- persistent CSR aggregation, 128-dim input, edge-loop unroll x2 -------------
__global__ __launch_bounds__(256) void agg_csr_din(
    const void* __restrict__ x, const int* __restrict__ offsets,
    const int* __restrict__ src, const float* __restrict__ ecn,
    const float* __restrict__ selfw, bf16* __restrict__ out,
    int n, const int* __restrict__ flags)
{
    int wave = threadIdx.x >> 6, lane = threadIdx.x & 63;
    int gw = blockIdx.x * 4 + wave;
    int nw = gridDim.x * 4;
    bool f32 = flags[1] != 0;

    for (int dst = gw; dst < n; dst += nw) {
        int s0 = offsets[dst], s1 = offsets[dst + 1];
        float sw = selfw[dst];
        float a0, a1;
        if (f32) {
            float2 v = ((const float2*)x)[(size_t)dst * 64 + lane];
            a0 = sw * v.x; a1 = sw * v.y;
        } else {
            unsigned u = ((const unsigned*)x)[(size_t)dst * 64 + lane];
            a0 = sw * bf2f((short)(u & 0xFFFF)); a1 = sw * bf2f((short)(u >> 16));
        }
        int p = s0;
        for (; p + 1 < s1; p += 2) {
            int sr0 = src[p], sr1 = src[p + 1];
            float n0 = ecn[p], n1 = ecn[p + 1];
            if (f32) {
                float2 v0 = ((const float2*)x)[(size_t)sr0 * 64 + lane];
                float2 v1 = ((const float2*)x)[(size_t)sr1 * 64 + lane];
                a0 += n0 * v0.x + n1 * v1.x;
                a1 += n0 * v0.y + n1 * v1.y;
            } else {
                unsigned u0 = ((const unsigned*)x)[(size_t)sr0 * 64 + lane];
                unsigned u1 = ((const unsigned*)x)[(size_t)sr1 * 64 + lane];
                a0 += n0 * bf2f((short)(u0 & 0xFFFF)) + n1 * bf2f((short)(u1 & 0xFFFF));
                a1 += n0 * bf2f((short)(u0 >> 16))    + n1 * bf2f((short)(u1 >> 16));
            }
        }
        if (p < s1) {
            int sr0 = src[p];
            float n0 = ecn[p];
            if (f32) {
                float2 v0 = ((const float2*)x)[(size_t)sr0 * 64 + lane];
                a0 += n0 * v0.x; a1 += n0 * v0.y;
            } else {
                unsigned u0 = ((const unsigned*)x)[(size_t)sr0 * 64 + lane];
                a0 += n0 * bf2f((short)(u0 & 0xFFFF)); a1 += n0 * bf2f((short)(u0 >> 16));
            }
        }
        ((unsigned*)out)[(size_t)dst * 64 + lane] =
            (unsigned)f2bfbits(a0) | ((unsigned)f2bfbits(a1) << 16);
    }
}

// -- persistent CSR aggregation (512-dim) with fused BN-affine+leaky, unroll x2 ----
__global__ __launch_bounds__(256) void agg_csr_bn(
    const bf16* __restrict__ h, const int* __restrict__ offsets,
    const int* __restrict__ src, const float* __restrict__ ecn,
    const float* __restrict__ selfw,
    const float* __restrict__ scale, const float* __restrict__ shift,
    bf16* __restrict__ y, int n)
{
    int wave = threadIdx.x >> 6, lane = threadIdx.x & 63;
    int f0 = lane * 8;
    int gw = blockIdx.x * 4 + wave;
    int nw = gridDim.x * 4;

    float sc[8], sh[8];
#pragma unroll
    for (int j = 0; j < 8; j++) { sc[j] = scale[f0 + j]; sh[j] = shift[f0 + j]; }

    for (int dst = gw; dst < n; dst += nw) {
        int s0 = offsets[dst], s1 = offsets[dst + 1];
        float sw = selfw[dst];
        short8 hv = *(const short8*)(h + (size_t)dst * HDIM + f0);
        float acc[8];
#pragma unroll
        for (int j = 0; j < 8; j++) {
            float t = sc[j] * bf2f(hv[j]) + sh[j];
            t = t > 0.f ? t : SLOPE * t;
            acc[j] = sw * t;
        }
        int p = s0;
        for (; p + 1 < s1; p += 2) {
            int sr0 = src[p], sr1 = src[p + 1];
            float n0 = ecn[p], n1 = ecn[p + 1];
            short8 v0 = *(const short8*)(h + (size_t)sr0 * HDIM + f0);
            short8 v1 = *(const short8*)(h + (size_t)sr1 * HDIM + f0);
#pragma unroll
            for (int j = 0; j < 8; j++) {
                float t0 = sc[j] * bf2f(v0[j]) + sh[j];
                t0 = t0 > 0.f ? t0 : SLOPE * t0;
                float t1 = sc[j] * bf2f(v1[j]) + sh[j];
                t1 = t1 > 0.f ? t1 : SLOPE * t1;
                acc[j] += n0 * t0 + n1 * t1;
            }
        }
        if (p < s1) {
            int sr0 = src[p];
            float n0 = ecn[p];
            short8 v0 = *(const short8*)(h + (size_t)sr0 * HDIM + f0);
#pragma unroll
            for (int j = 0; j < 8; j++) {
                float t0 = sc[j] * bf2f(v0[j]) + sh[j];
                t0 = t0 > 0.f ? t0 : SLOPE * t0;
                acc[j] += n0 * t0;
            }
        }
        short8 o;
#pragma unroll
        for (int j = 0; j < 8; j++) ((bf16*)&o)[j] = __float2bfloat16(acc[j]);
        *(short8*)(y + (size_t)dst * HDIM + f0) = o;
    }
}

// ------ BN coeffs from striped partials; re-zeros gpart for the next layer --------
__global__ void bn_final(float* __restrict__ gpart,
                         const void* __restrict__ gamma, const void* __restrict__ beta,
                         float* __restrict__ scale, float* __restrict__ shift,
                         float invN, const int* __restrict__ flags)
{
    int f = threadIdx.x;
    float s = 0.f, q = 0.f;
#pragma unroll
    for (int k = 0; k < STRIPES; k++) {
        s += gpart[(size_t)k * 2 * HDIM + f];
        q += gpart[(size_t)k * 2 * HDIM + HDIM + f];
        gpart[(size_t)k * 2 * HDIM + f] = 0.f;
        gpart[(size_t)k * 2 * HDIM + HDIM + f] = 0.f;
    }
    float g = flags[1] ? ((const float*)gamma)[f]
                       : __bfloat162float(((const bf16*)gamma)[f]);
    float b = flags[1] ? ((const float*)beta)[f]
                       : __bfloat162float(((const bf16*)beta)[f]);
    float mu = s * invN;
    float var = fmaxf(q * invN - mu * mu, 0.f);
    float inv = rsqrtf(var + BN_EPS);
    float sc = g * inv;
    scale[f] = sc;
    shift[f] = b - mu * sc;
}

// ---- pooling: wave per graph, 16B/lane loads, fused BN+leaky (monotone) ----------
__global__ __launch_bounds__(256) void pool_fused(
    const bf16* __restrict__ y, const int* __restrict__ batch,
    const float* __restrict__ scale, const float* __restrict__ shift,
    bf16* __restrict__ pooled, int n, int G)
{
    int wave = threadIdx.x >> 6, lane = threadIdx.x & 63;
    int g = blockIdx.x * 4 + wave;
    if (g >= G) return;
    int f0 = lane * 8;

    int lo = 0, hi = n;
    while (lo < hi) { int mid = (lo + hi) >> 1; if (batch[mid] < g) lo = mid + 1; else hi = mid; }
    int s = lo;
    hi = n;
    while (lo < hi) { int mid = (lo + hi) >> 1; if (batch[mid] <= g) lo = mid + 1; else hi = mid; }
    int e = lo;

    float mx[8], mn[8];
#pragma unroll
    for (int j = 0; j < 8; j++) { mx[j] = -3.0e38f; mn[j] = 3.0e38f; }

    int rr = s;
    for (; rr + 1 < e; rr += 2) {   // two independent 1KB row loads in flight
        short8 v0 = *(const short8*)(y + (size_t)rr * HDIM + f0);
        short8 v1 = *(const short8*)(y + (size_t)(rr + 1) * HDIM + f0);
#pragma unroll
        for (int j = 0; j < 8; j++) {
            float a = bf2f(v0[j]), b = bf2f(v1[j]);
            mx[j] = fmaxf(mx[j], fmaxf(a, b));
            mn[j] = fminf(mn[j], fminf(a, b));
        }
    }
    if (rr < e) {
        short8 v0 = *(const short8*)(y + (size_t)rr * HDIM + f0);
#pragma unroll
        for (int j = 0; j < 8; j++) {
            float a = bf2f(v0[j]);
            mx[j] = fmaxf(mx[j], a);
            mn[j] = fminf(mn[j], a);
        }
    }

    short8 o;
#pragma unroll
    for (int j = 0; j < 8; j++) {
        float outv = 0.f;
        if (s < e) {
            float sc = scale[f0 + j];
            float t = sc * (sc >= 0.f ? mx[j] : mn[j]) + shift[f0 + j];
            outv = t > 0.f ? t : SLOPE * t;
        }
        ((bf16*)&o)[j] = __float2bfloat16(outv);
    }
    *(short8*)(pooled + (size_t)g * HDIM + f0) = o;
}

// ---------------- orchestration --------------------------------------------------
extern "C" void kernel_launch(void* const* d_in, const int* in_sizes, int n_in,
                              void* d_out, int out_size, void* d_ws, size_t ws_size,
                              hipStream_t stream)
{
    const void* x     = d_in[0];
    const int*  ei    = (const int*)d_in[1];
    const int*  batch = (const int*)d_in[2];
    // d_in[4]=b1, d_in[8]=b2 cancel in training-mode BatchNorm — unused.

    const int N   = in_sizes[2];
    const int E   = in_sizes[1] / 2;
    const int DIN = 128;
    const int OUT = 256;
    const int G   = out_size / OUT;
    const int Mp  = (N + 127) & ~127;
    const int MB  = Mp / 128;
    const int MB8 = (MB + 7) & ~7;

    // workspace carve — ~237 MB
    char* p = (char*)d_ws;
    bf16* B1     = (bf16*)p;  p += (size_t)Mp * HDIM * sizeof(bf16);
    bf16* B2     = (bf16*)p;  p += (size_t)Mp * HDIM * sizeof(bf16);
    bf16* Q      = (bf16*)p;  p += (size_t)Mp * DIN * sizeof(bf16);
    bf16* W1T    = (bf16*)p;  p += (size_t)HDIM * DIN * sizeof(bf16);
    bf16* W2T    = (bf16*)p;  p += (size_t)HDIM * HDIM * sizeof(bf16);
    bf16* WfT    = (bf16*)p;  p += (size_t)OUT * HDIM * sizeof(bf16);
    bf16* bfbf   = (bf16*)p;  p += 512 * sizeof(bf16);
    int* ei32    = (int*)p;   p += (size_t)2 * E * sizeof(int);
    int* batch32 = (int*)p;   p += (size_t)N * sizeof(int);
    float* dinv  = (float*)p; p += (size_t)N * sizeof(float);
    float* selfw = (float*)p; p += (size_t)N * sizeof(float);
    int* offsets = (int*)p;   p += (size_t)(N + 4) * sizeof(int);
    int* cursor  = (int*)p;   p += (size_t)N * sizeof(int);
    int* srcarr  = (int*)p;   p += (size_t)E * sizeof(int);
    float* ecn   = (float*)p; p += (size_t)E * sizeof(float);
    int* bsum    = (int*)p;   p += 1024 * sizeof(int);
    float* gpart = (float*)p; p += (size_t)STRIPES * 2 * HDIM * sizeof(float);
    float* sc1   = (float*)p; p += HDIM * sizeof(float);
    float* sh1   = (float*)p; p += HDIM * sizeof(float);
    float* sc2   = (float*)p; p += HDIM * sizeof(float);
    float* sh2   = (float*)p; p += HDIM * sizeof(float);
    int* flags   = (int*)p;   p += 4 * sizeof(int);

    // ---- detection (+gpart zero) + fused conversions + degree count ----
    detect_types<<<1, 256, 0, stream>>>(ei, (const unsigned*)x, flags, gpart);
    hipMemsetAsync(cursor, 0, (size_t)N * sizeof(int), stream);
    conv_all_idx<<<(2 * E + N + 255) / 256, 256, 0, stream>>>(
        ei, batch, ei32, batch32, cursor, 2 * E, N, flags);
    wt_conv_all<<<(128 * 512 + 512 * 512 + 512 * 256 + 256 + 255) / 256, 256, 0, stream>>>(
        d_in[3], d_in[7], d_in[11], d_in[12], W1T, W2T, WfT, bfbf, flags);

    const int* rows = ei32;
    const int* cols = ei32 + E;

    // ---- CSR + degrees + per-edge norms ----
    finalize_deg<<<(N + 255) / 256, 256, 0, stream>>>(cursor, dinv, selfw, N);
    int nb = (N + 511) / 512;
    scan_part<<<nb, 256, 0, stream>>>(cursor, offsets, bsum, N);
    scan_tops<<<1, 1024, 0, stream>>>(bsum, nb);
    scan_add<<<nb, 256, 0, stream>>>(offsets, bsum, N, E);
    hipMemsetAsync(cursor, 0, (size_t)N * sizeof(int), stream);
    scatter_edges<<<(E + 255) / 256, 256, 0, stream>>>(rows, cols, offsets, cursor,
                                                       dinv, srcarr, ecn, E);

    int gemm_blocks = MB8 * (HDIM / 128);

    // ---- layer 1: aggregate x (agg is linear), GEMM w/ fused stats ----
    agg_csr_din<<<2048, 256, 0, stream>>>(x, offsets, srcarr, ecn, selfw, Q, N, flags);
    gemm_m97<true><<<gemm_blocks, 256, 0, stream>>>(
        Q, W1T, B2, nullptr, N, DIN, HDIM, nullptr, gpart, MB);
    bn_final<<<1, HDIM, 0, stream>>>(gpart, d_in[5], d_in[6], sc1, sh1, 1.0f / N, flags);

    // ---- layer 2: aggregate RAW conv1 output w/ fused BN+leaky, GEMM w/ stats ----
    agg_csr_bn<<<2048, 256, 0, stream>>>(B2, offsets, srcarr, ecn, selfw, sc1, sh1, B1, N);
    gemm_m97<true><<<gemm_blocks, 256, 0, stream>>>(
        B1, W2T, B2, nullptr, N, HDIM, HDIM, nullptr, gpart, MB);
    bn_final<<<1, HDIM, 0, stream>>>(gpart, d_in[9], d_in[10], sc2, sh2, 1.0f / N, flags);

    // ---- pool (wave/graph, fused BN+leaky) + head GEMM ----
    pool_fused<<<(G + 3) / 4, 256, 0, stream>>>(B2, batch32, sc2, sh2, Q, N, G);
    gemm_m97<false><<<(G / 128) * (OUT / 128), 256, 0, stream>>>(
        Q, WfT, d_out, bfbf, G, HDIM, OUT, flags + 1, nullptr, G / 128);
}

// Round 20
// 520.281 us; speedup vs baseline: 1.1327x; 1.0026x over previous
//
#include <hip/hip_runtime.h>
#include <hip/hip_bf16.h>

typedef __hip_bfloat16 bf16;
typedef __attribute__((ext_vector_type(8))) short short8;
typedef __attribute__((ext_vector_type(4))) float f32x4;

#define HDIM 512
#define SLOPE 0.01f
#define BN_EPS 1e-5f
#define STRIPES 8

__device__ inline float bf2f(short s) {
    unsigned u = ((unsigned)(unsigned short)s) << 16;
    return __builtin_bit_cast(float, u);
}
__device__ inline unsigned short f2bfbits(float v) {
    bf16 h = __float2bfloat16(v);
    return (unsigned short)__builtin_bit_cast(short, h);
}

// packed edge record: src node + precomputed norm (single 8B load in gather loop)
struct EdgeRec { int src; float nm; };

// ---------------- dtype detection + gpart zero-init ----------------
__global__ void detect_types(const int* __restrict__ ei, const unsigned* __restrict__ xw,
                             int* __restrict__ flags, float* __restrict__ gpart) {
    __shared__ int nzhi, okbf;
    if (threadIdx.x == 0) { nzhi = 0; okbf = 0; }
    __syncthreads();
    int lo = 0, ok = 0;
    for (int i = threadIdx.x; i < 2048; i += 256)
        if (ei[2 * i + 1] != 0) lo++;
    for (int i = threadIdx.x; i < 1024; i += 256) {
        unsigned w = (xw[i] & 0xFFFFu) << 16;
        float av = fabsf(__builtin_bit_cast(float, w));
        if (av > 0.0009f && av < 64.0f) ok++;
    }
    for (int i = threadIdx.x; i < STRIPES * 2 * HDIM; i += 256) gpart[i] = 0.f;
    if (lo) atomicAdd(&nzhi, lo);
    if (ok) atomicAdd(&okbf, ok);
    __syncthreads();
    if (threadIdx.x == 0) {
        flags[0] = (nzhi == 0) ? 1 : 0;
        flags[1] = (okbf < 512) ? 1 : 0;
    }
}

// convert ei (2E) + batch (N) to int32, and count in-degrees from cols on the fly
__global__ void conv_all_idx(const int* __restrict__ ei, const int* __restrict__ batch,
                             int* __restrict__ ei32, int* __restrict__ batch32,
                             int* __restrict__ cnt, int e2, int n,
                             const int* __restrict__ flags) {
    int i = blockIdx.x * blockDim.x + threadIdx.x;
    int i64 = flags[0];
    if (i < e2) {
        int v = i64 ? (int)((const long long*)ei)[i] : ei[i];
        ei32[i] = v;
        if (i >= e2 / 2) atomicAdd(&cnt[v], 1);   // cols half
    } else if (i < e2 + n) {
        int j = i - e2;
        batch32[j] = i64 ? (int)((const long long*)batch)[j] : batch[j];
    }
}

// convert + transpose all weights and the final bias in one launch
__global__ void wt_conv_all(const void* __restrict__ W1, const void* __restrict__ W2,
                            const void* __restrict__ Wf, const void* __restrict__ bf_,
                            bf16* __restrict__ W1T, bf16* __restrict__ W2T,
                            bf16* __restrict__ WfT, bf16* __restrict__ bfbf,
                            const int* __restrict__ flags) {
    const int S1 = 128 * 512, S2 = 512 * 512, S3 = 512 * 256;
    int idx = blockIdx.x * 256 + threadIdx.x;
    bool f32 = flags[1] != 0;
    if (idx < S1) {
        int nn = idx / 128, k = idx - nn * 128;   // K=128, Nn=512
        float v = f32 ? ((const float*)W1)[(size_t)k * 512 + nn]
                      : __bfloat162float(((const bf16*)W1)[(size_t)k * 512 + nn]);
        W1T[idx] = __float2bfloat16(v);
    } else if (idx < S1 + S2) {
        int t = idx - S1;
        int nn = t / 512, k = t - nn * 512;       // K=512, Nn=512
        float v = f32 ? ((const float*)W2)[(size_t)k * 512 + nn]
                      : __bfloat162float(((const bf16*)W2)[(size_t)k * 512 + nn]);
        W2T[t] = __float2bfloat16(v);
    } else if (idx < S1 + S2 + S3) {
        int t = idx - S1 - S2;
        int nn = t / 512, k = t - nn * 512;       // K=512, Nn=256
        float v = f32 ? ((const float*)Wf)[(size_t)k * 256 + nn]
                      : __bfloat162float(((const bf16*)Wf)[(size_t)k * 256 + nn]);
        WfT[t] = __float2bfloat16(v);
    } else if (idx < S1 + S2 + S3 + 256) {
        int t = idx - S1 - S2 - S3;
        float v = f32 ? ((const float*)bf_)[t]
                      : __bfloat162float(((const bf16*)bf_)[t]);
        bfbf[t] = __float2bfloat16(v);
    }
}

__global__ void finalize_deg(const int* __restrict__ cnt, float* __restrict__ dinv,
                             float* __restrict__ selfw, int n) {
    int i = blockIdx.x * blockDim.x + threadIdx.x;
    if (i < n) {
        float d = (float)cnt[i] + 2.0f;
        dinv[i] = rsqrtf(d);
        selfw[i] = 2.0f / d;
    }
}

// ---------------- parallel exclusive scan (3 kernels, 512 elems/block) -----------
__global__ __launch_bounds__(256) void scan_part(
    const int* __restrict__ counts, int* __restrict__ offsets,
    int* __restrict__ bsum, int n)
{
    __shared__ int s[512];
    int b = blockIdx.x;
    int base = b * 512;
    int t = threadIdx.x;
    s[t]       = (base + t       < n) ? counts[base + t]       : 0;
    s[t + 256] = (base + t + 256 < n) ? counts[base + t + 256] : 0;

    int offset = 1;
    for (int d = 256; d > 0; d >>= 1) {
        __syncthreads();
        if (t < d) {
            int ai = offset * (2 * t + 1) - 1;
            int bi = offset * (2 * t + 2) - 1;
            s[bi] += s[ai];
        }
        offset <<= 1;
    }
    __syncthreads();
    if (t == 0) { bsum[b] = s[511]; s[511] = 0; }
    for (int d = 1; d < 512; d <<= 1) {
        offset >>= 1;
        __syncthreads();
        if (t < d) {
            int ai = offset * (2 * t + 1) - 1;
            int bi = offset * (2 * t + 2) - 1;
            int tmp = s[ai]; s[ai] = s[bi]; s[bi] += tmp;
        }
    }
    __syncthreads();
    if (base + t < n)       offsets[base + t]       = s[t];
    if (base + t + 256 < n) offsets[base + t + 256] = s[t + 256];
}

__global__ __launch_bounds__(1024) void scan_tops(int* __restrict__ bsum, int nb) {
    __shared__ int s[1024];
    int t = threadIdx.x;
    s[t] = (t < nb) ? bsum[t] : 0;
    __syncthreads();
    for (int off = 1; off < 1024; off <<= 1) {
        int v = (t >= off) ? s[t - off] : 0;
        __syncthreads();
        s[t] += v;
        __syncthreads();
    }
    if (t < nb) bsum[t] = (t == 0) ? 0 : s[t - 1];   // exclusive
}

__global__ __launch_bounds__(256) void scan_add(
    int* __restrict__ offsets, const int* __restrict__ bsum, int n, int e)
{
    int b = blockIdx.x;
    int base = b * 512;
    int add = bsum[b];
    int t = threadIdx.x;
    if (base + t < n)       offsets[base + t]       += add;
    if (base + t + 256 < n) offsets[base + t + 256] += add;
    if (b == 0 && t == 0) offsets[n] = e;
}

// scatter edges into CSR order as packed {src, norm} records
__global__ void scatter_edges(const int* __restrict__ rows, const int* __restrict__ cols,
                              const int* __restrict__ offsets, int* __restrict__ cursor,
                              const float* __restrict__ dinv,
                              EdgeRec* __restrict__ er, int e)
{
    int i = blockIdx.x * blockDim.x + threadIdx.x;
    if (i < e) {
        int d = cols[i];
        int r = rows[i];
        int pos = offsets[d] + atomicAdd(&cursor[d], 1);
        EdgeRec rec;
        rec.src = r;
        rec.nm = dinv[d] * dinv[r];
        er[pos] = rec;
    }
}

// ------ m97-style GEMM, BK=32, XCD-swizzled grid, 4 waves/EU cap, LDS XOR-swizzle -
template<bool STATS>
__global__ __launch_bounds__(256, 4) void gemm_m97(
    const bf16* __restrict__ A, const bf16* __restrict__ BT,
    void* __restrict__ C, const bf16* __restrict__ bias,
    int M, int K, int N, const int* __restrict__ cf32,
    float* __restrict__ gpart, int MB)
{
    __shared__ bf16 As[128 * 32];
    __shared__ bf16 Bs[128 * 32];
    __shared__ float ssum[STATS ? 128 : 1];
    __shared__ float ssq[STATS ? 128 : 1];

    int NBN = N >> 7;
    int id = blockIdx.x;
    int grp = id / (8 * NBN);
    int loc = id - grp * 8 * NBN;
    int mi = loc & 7;
    int nblk = loc >> 3;
    int mblk = grp * 8 + mi;
    if (mblk >= MB) return;

    int tid = threadIdx.x;
    int wave = tid >> 6, lane = tid & 63, q = lane >> 4, r = lane & 15;
    int wm = (wave >> 1) * 64, wn = (wave & 1) * 64;
    int m0 = mblk * 128, n0 = nblk * 128;
    bool c32 = cf32 && *cf32;

    if constexpr (STATS) {
        if (tid < 128) { ssum[tid] = 0.f; ssq[tid] = 0.f; }
    }

    int lrow = lane >> 2;
    int lcol = (((lane & 3) ^ ((lane >> 3) & 3)) * 8);   // XOR-swizzled source chunk
    int aoff = (q ^ ((r >> 1) & 3)) * 8;                 // fragment-read swizzle

    f32x4 acc[4][4];
#pragma unroll
    for (int mi2 = 0; mi2 < 4; mi2++)
#pragma unroll
        for (int ni = 0; ni < 4; ni++)
            acc[mi2][ni] = {0.f, 0.f, 0.f, 0.f};

    for (int k0 = 0; k0 < K; k0 += 32) {
#pragma unroll
        for (int i = 0; i < 2; i++) {
            int c = wave * 2 + i;
            const bf16* ga = A  + (size_t)(m0 + c * 16 + lrow) * K + k0 + lcol;
            const bf16* gb = BT + (size_t)(n0 + c * 16 + lrow) * K + k0 + lcol;
            __builtin_amdgcn_global_load_lds(
                (const __attribute__((address_space(1))) unsigned*)ga,
                (__attribute__((address_space(3))) unsigned*)(As + c * 512), 16, 0, 0);
            __builtin_amdgcn_global_load_lds(
                (const __attribute__((address_space(1))) unsigned*)gb,
                (__attribute__((address_space(3))) unsigned*)(Bs + c * 512), 16, 0, 0);
        }
        __syncthreads();

        short8 a[4], b[4];
#pragma unroll
        for (int mi2 = 0; mi2 < 4; mi2++) a[mi2] = *(const short8*)&As[(wm + mi2 * 16 + r) * 32 + aoff];
#pragma unroll
        for (int ni = 0; ni < 4; ni++) b[ni] = *(const short8*)&Bs[(wn + ni * 16 + r) * 32 + aoff];
#pragma unroll
        for (int mi2 = 0; mi2 < 4; mi2++)
#pragma unroll
            for (int ni = 0; ni < 4; ni++)
                acc[mi2][ni] = __builtin_amdgcn_mfma_f32_16x16x32_bf16(a[mi2], b[ni], acc[mi2][ni], 0, 0, 0);
        __syncthreads();
    }

#pragma unroll
    for (int mi2 = 0; mi2 < 4; mi2++) {
#pragma unroll
        for (int ni = 0; ni < 4; ni++) {
            int gn = n0 + wn + ni * 16 + r;
            float bv = bias ? __bfloat162float(bias[gn]) : 0.f;
#pragma unroll
            for (int reg = 0; reg < 4; reg++) {
                int gm = m0 + wm + mi2 * 16 + q * 4 + reg;
                if (gm < M) {
                    float val = acc[mi2][ni][reg] + bv;
                    if (c32) ((float*)C)[(size_t)gm * N + gn] = val;
                    else     ((bf16*)C)[(size_t)gm * N + gn] = __float2bfloat16(val);
                }
            }
        }
    }

    if constexpr (STATS) {
#pragma unroll
        for (int ni = 0; ni < 4; ni++) {
            float cs = 0.f, cq = 0.f;
#pragma unroll
            for (int mi2 = 0; mi2 < 4; mi2++)
#pragma unroll
                for (int reg = 0; reg < 4; reg++) {
                    int gm = m0 + wm + mi2 * 16 + q * 4 + reg;
                    if (gm < M) {
                        float v = acc[mi2][ni][reg];
                        cs += v; cq += v * v;
                    }
                }
            int c = wn + ni * 16 + r;
            atomicAdd(&ssum[c], cs);
            atomicAdd(&ssq[c], cq);
        }
        __syncthreads();
        if (tid < 128) {
            float* base = gpart + (size_t)(mblk & (STRIPES - 1)) * 2 * HDIM;
            atomicAdd(&base[n0 + tid], ssum[tid]);
            atomicAdd(&base[HDIM + n0 + tid], ssq[tid]);
        }
    }
}

// ----- persistent CSR aggregation, 128-dim input, edge-loop unroll x2 -------------
__global__ __launch_bounds__(256) void agg_csr_din(
    const void* __restrict__ x, const int* __restrict__ offsets,
    const EdgeRec* __restrict__ er, const float* __restrict__ selfw,
    bf16* __restrict__ out, int n, const int* __restrict__ flags)
{
    int wave = threadIdx.x >> 6, lane = threadIdx.x & 63;
    int gw = blockIdx.x * 4 + wave;
    int nw = gridDim.x * 4;
    bool f32 = flags[1] != 0;

    for (int dst = gw; dst < n; dst += nw) {
        int s0 = offsets[dst], s1 = offsets[dst + 1];
        float sw = selfw[dst];
        float a0, a1;
        if (f32) {
            float2 v = ((const float2*)x)[(size_t)dst * 64 + lane];
            a0 = sw * v.x; a1 = sw * v.y;
        } else {
            unsigned u = ((const unsigned*)x)[(size_t)dst * 64 + lane];
            a0 = sw * bf2f((short)(u & 0xFFFF)); a1 = sw * bf2f((short)(u >> 16));
        }
        int p = s0;
        for (; p + 1 < s1; p += 2) {
            EdgeRec e0 = er[p], e1 = er[p + 1];
            if (f32) {
                float2 v0 = ((const float2*)x)[(size_t)e0.src * 64 + lane];
                float2 v1 = ((const float2*)x)[(size_t)e1.src * 64 + lane];
                a0 += e0.nm * v0.x + e1.nm * v1.x;
                a1 += e0.nm * v0.y + e1.nm * v1.y;
            } else {
                unsigned u0 = ((const unsigned*)x)[(size_t)e0.src * 64 + lane];
                unsigned u1 = ((const unsigned*)x)[(size_t)e1.src * 64 + lane];
                a0 += e0.nm * bf2f((short)(u0 & 0xFFFF)) + e1.nm * bf2f((short)(u1 & 0xFFFF));
                a1 += e0.nm * bf2f((short)(u0 >> 16))    + e1.nm * bf2f((short)(u1 >> 16));
            }
        }
        if (p < s1) {
            EdgeRec e0 = er[p];
            if (f32) {
                float2 v0 = ((const float2*)x)[(size_t)e0.src * 64 + lane];
                a0 += e0.nm * v0.x; a1 += e0.nm * v0.y;
            } else {
                unsigned u0 = ((const unsigned*)x)[(size_t)e0.src * 64 + lane];
                a0 += e0.nm * bf2f((short)(u0 & 0xFFFF)); a1 += e0.nm * bf2f((short)(u0 >> 16));
            }
        }
        ((unsigned*)out)[(size_t)dst * 64 + lane] =
            (unsigned)f2bfbits(a0) | ((unsigned)f2bfbits(a1) << 16);
    }
}

// -- persistent CSR aggregation (512-dim) with fused BN-affine+leaky, unroll x2 ----
__global__ __launch_bounds__(256) void agg_csr_bn(
    const bf16* __restrict__ h, const int* __restrict__ offsets,
    const EdgeRec* __restrict__ er, const float* __restrict__ selfw,
    const float* __restrict__ scale, const float* __restrict__ shift,
    bf16* __restrict__ y, int n)
{
    int wave = threadIdx.x >> 6, lane = threadIdx.x & 63;
    int f0 = lane * 8;
    int gw = blockIdx.x * 4 + wave;
    int nw = gridDim.x * 4;

    float sc[8], sh[8];
#pragma unroll
    for (int j = 0; j < 8; j++) { sc[j] = scale[f0 + j]; sh[j] = shift[f0 + j]; }

    for (int dst = gw; dst < n; dst += nw) {
        int s0 = offsets[dst], s1 = offsets[dst + 1];
        float sw = selfw[dst];
        short8 hv = *(const short8*)(h + (size_t)dst * HDIM + f0);
        float acc[8];
#pragma unroll
        for (int j = 0; j < 8; j++) {
            float t = sc[j] * bf2f(hv[j]) + sh[j];
            t = t > 0.f ? t : SLOPE * t;
            acc[j] = sw * t;
        }
        int p = s0;
        for (; p + 1 < s1; p += 2) {
            EdgeRec e0 = er[p], e1 = er[p + 1];
            short8 v0 = *(const short8*)(h + (size_t)e0.src * HDIM + f0);
            short8 v1 = *(const short8*)(h + (size_t)e1.src * HDIM + f0);
#pragma unroll
            for (int j = 0; j < 8; j++) {
                float t0 = sc[j] * bf2f(v0[j]) + sh[j];
                t0 = t0 > 0.f ? t0 : SLOPE * t0;
                float t1 = sc[j] * bf2f(v1[j]) + sh[j];
                t1 = t1 > 0.f ? t1 : SLOPE * t1;
                acc[j] += e0.nm * t0 + e1.nm * t1;
            }
        }
        if (p < s1) {
            EdgeRec e0 = er[p];
            short8 v0 = *(const short8*)(h + (size_t)e0.src * HDIM + f0);
#pragma unroll
            for (int j = 0; j < 8; j++) {
                float t0 = sc[j] * bf2f(v0[j]) + sh[j];
                t0 = t0 > 0.f ? t0 : SLOPE * t0;
                acc[j] += e0.nm * t0;
            }
        }
        short8 o;
#pragma unroll
        for (int j = 0; j < 8; j++) ((bf16*)&o)[j] = __float2bfloat16(acc[j]);
        *(short8*)(y + (size_t)dst * HDIM + f0) = o;
    }
}

// ------ BN coeffs from striped partials; re-zeros gpart for the next layer --------
__global__ void bn_final(float* __restrict__ gpart,
                         const void* __restrict__ gamma, const void* __restrict__ beta,
                         float* __restrict__ scale, float* __restrict__ shift,
                         float invN, const int* __restrict__ flags)
{
    int f = threadIdx.x;
    float s = 0.f, q = 0.f;
#pragma unroll
    for (int k = 0; k < STRIPES; k++) {
        s += gpart[(size_t)k * 2 * HDIM + f];
        q += gpart[(size_t)k * 2 * HDIM + HDIM + f];
        gpart[(size_t)k * 2 * HDIM + f] = 0.f;
        gpart[(size_t)k * 2 * HDIM + HDIM + f] = 0.f;
    }
    float g = flags[1] ? ((const float*)gamma)[f]
                       : __bfloat162float(((const bf16*)gamma)[f]);
    float b = flags[1] ? ((const float*)beta)[f]
                       : __bfloat162float(((const bf16*)beta)[f]);
    float mu = s * invN;
    float var = fmaxf(q * invN - mu * mu, 0.f);
    float inv = rsqrtf(var + BN_EPS);
    float sc = g * inv;
    scale[f] = sc;
    shift[f] = b - mu * sc;
}

// ---- pooling: wave per graph, 16B/lane loads, fused BN+leaky (monotone) ----------
__global__ __launch_bounds__(256) void pool_fused(
    const bf16* __restrict__ y, const int* __restrict__ batch,
    const float* __restrict__ scale, const float* __restrict__ shift,
    bf16* __restrict__ pooled, int n, int G)
{
    int wave = threadIdx.x >> 6, lane = threadIdx.x & 63;
    int g = blockIdx.x * 4 + wave;
    if (g >= G) return;
    int f0 = lane * 8;

    int lo = 0, hi = n;
    while (lo < hi) { int mid = (lo + hi) >> 1; if (batch[mid] < g) lo = mid + 1; else hi = mid; }
    int s = lo;
    hi = n;
    while (lo < hi) { int mid = (lo + hi) >> 1; if (batch[mid] <= g) lo = mid + 1; else hi = mid; }
    int e = lo;

    float mx[8], mn[8];
#pragma unroll
    for (int j = 0; j < 8; j++) { mx[j] = -3.0e38f; mn[j] = 3.0e38f; }

    int rr = s;
    for (; rr + 1 < e; rr += 2) {
        short8 v0 = *(const short8*)(y + (size_t)rr * HDIM + f0);
        short8 v1 = *(const short8*)(y + (size_t)(rr + 1) * HDIM + f0);
#pragma unroll
        for (int j = 0; j < 8; j++) {
            float a = bf2f(v0[j]), b = bf2f(v1[j]);
            mx[j] = fmaxf(mx[j], fmaxf(a, b));
            mn[j] = fminf(mn[j], fminf(a, b));
        }
    }
    if (rr < e) {
        short8 v0 = *(const short8*)(y + (size_t)rr * HDIM + f0);
#pragma unroll
        for (int j = 0; j < 8; j++) {
            float a = bf2f(v0[j]);
            mx[j] = fmaxf(mx[j], a);
            mn[j] = fminf(mn[j], a);
        }
    }

    short8 o;
#pragma unroll
    for (int j = 0; j < 8; j++) {
        float outv = 0.f;
        if (s < e) {
            float sc = scale[f0 + j];
            float t = sc * (sc >= 0.f ? mx[j] : mn[j]) + shift[f0 + j];
            outv = t > 0.f ? t : SLOPE * t;
        }
        ((bf16*)&o)[j] = __float2bfloat16(outv);
    }
    *(short8*)(pooled + (size_t)g * HDIM + f0) = o;
}

// ---------------- orchestration --------------------------------------------------
extern "C" void kernel_launch(void* const* d_in, const int* in_sizes, int n_in,
                              void* d_out, int out_size, void* d_ws, size_t ws_size,
                              hipStream_t stream)
{
    const void* x     = d_in[0];
    const int*  ei    = (const int*)d_in[1];
    const int*  batch = (const int*)d_in[2];
    // d_in[4]=b1, d_in[8]=b2 cancel in training-mode BatchNorm — unused.

    const int N   = in_sizes[2];
    const int E   = in_sizes[1] / 2;
    const int DIN = 128;
    const int OUT = 256;
    const int G   = out_size / OUT;
    const int Mp  = (N + 127) & ~127;
    const int MB  = Mp / 128;
    const int MB8 = (MB + 7) & ~7;

    // workspace carve — ~238 MB
    char* p = (char*)d_ws;
    bf16* B1     = (bf16*)p;  p += (size_t)Mp * HDIM * sizeof(bf16);
    bf16* B2     = (bf16*)p;  p += (size_t)Mp * HDIM * sizeof(bf16);
    bf16* Q      = (bf16*)p;  p += (size_t)Mp * DIN * sizeof(bf16);
    bf16* W1T    = (bf16*)p;  p += (size_t)HDIM * DIN * sizeof(bf16);
    bf16* W2T    = (bf16*)p;  p += (size_t)HDIM * HDIM * sizeof(bf16);
    bf16* WfT    = (bf16*)p;  p += (size_t)OUT * HDIM * sizeof(bf16);
    bf16* bfbf   = (bf16*)p;  p += 512 * sizeof(bf16);
    int* ei32    = (int*)p;   p += (size_t)2 * E * sizeof(int);
    int* batch32 = (int*)p;   p += (size_t)N * sizeof(int);
    float* dinv  = (float*)p; p += (size_t)N * sizeof(float);
    float* selfw = (float*)p; p += (size_t)N * sizeof(float);
    int* offsets = (int*)p;   p += (size_t)(N + 4) * sizeof(int);
    int* cursor  = (int*)p;   p += (size_t)N * sizeof(int);
    EdgeRec* er  = (EdgeRec*)p; p += (size_t)E * sizeof(EdgeRec);
    int* bsum    = (int*)p;   p += 1024 * sizeof(int);
    float* gpart = (float*)p; p += (size_t)STRIPES * 2 * HDIM * sizeof(float);
    float* sc1   = (float*)p; p += HDIM * sizeof(float);
    float* sh1   = (float*)p; p += HDIM * sizeof(float);
    float* sc2   = (float*)p; p += HDIM * sizeof(float);
    float* sh2   = (float*)p; p += HDIM * sizeof(float);
    int* flags   = (int*)p;   p += 4 * sizeof(int);

    // ---- detection (+gpart zero) + fused conversions + degree count ----
    detect_types<<<1, 256, 0, stream>>>(ei, (const unsigned*)x, flags, gpart);
    hipMemsetAsync(cursor, 0, (size_t)N * sizeof(int), stream);
    conv_all_idx<<<(2 * E + N + 255) / 256, 256, 0, stream>>>(
        ei, batch, ei32, batch32, cursor, 2 * E, N, flags);
    wt_conv_all<<<(128 * 512 + 512 * 512 + 512 * 256 + 256 + 255) / 256, 256, 0, stream>>>(
        d_in[3], d_in[7], d_in[11], d_in[12], W1T, W2T, WfT, bfbf, flags);

    const int* rows = ei32;
    const int* cols = ei32 + E;

    // ---- CSR + degrees + packed edge records ----
    finalize_deg<<<(N + 255) / 256, 256, 0, stream>>>(cursor, dinv, selfw, N);
    int nb = (N + 511) / 512;
    scan_part<<<nb, 256, 0, stream>>>(cursor, offsets, bsum, N);
    scan_tops<<<1, 1024, 0, stream>>>(bsum, nb);
    scan_add<<<nb, 256, 0, stream>>>(offsets, bsum, N, E);
    hipMemsetAsync(cursor, 0, (size_t)N * sizeof(int), stream);
    scatter_edges<<<(E + 255) / 256, 256, 0, stream>>>(rows, cols, offsets, cursor,
                                                       dinv, er, E);

    int gemm_blocks = MB8 * (HDIM / 128);

    // ---- layer 1: aggregate x (agg is linear), GEMM w/ fused stats ----
    agg_csr_din<<<2048, 256, 0, stream>>>(x, offsets, er, selfw, Q, N, flags);
    gemm_m97<true><<<gemm_blocks, 256, 0, stream>>>(
        Q, W1T, B2, nullptr, N, DIN, HDIM, nullptr, gpart, MB);
    bn_final<<<1, HDIM, 0, stream>>>(gpart, d_in[5], d_in[6], sc1, sh1, 1.0f / N, flags);

    // ---- layer 2: aggregate RAW conv1 output w/ fused BN+leaky, GEMM w/ stats ----
    agg_csr_bn<<<2048, 256, 0, stream>>>(B2, offsets, er, selfw, sc1, sh1, B1, N);
    gemm_m97<true><<<gemm_blocks, 256, 0, stream>>>(
        B1, W2T, B2, nullptr, N, HDIM, HDIM, nullptr, gpart, MB);
    bn_final<<<1, HDIM, 0, stream>>>(gpart, d_in[9], d_in[10], sc2, sh2, 1.0f / N, flags);

    // ---- pool (wave/graph, fused BN+leaky) + head GEMM ----
    pool_fused<<<(G + 3) / 4, 256, 0, stream>>>(B2, batch32, sc2, sh2, Q, N, G);
    gemm_m97<false><<<(G / 128) * (OUT / 128), 256, 0, stream>>>(
        Q, WfT, d_out, bfbf, G, HDIM, OUT, flags + 1, nullptr, G / 128);
}